// Round 5
// baseline (1700.578 us; speedup 1.0000x reference)
//
#include <hip/hip_runtime.h>

typedef float f32x4 __attribute__((ext_vector_type(4)));
typedef float f32x16 __attribute__((ext_vector_type(16)));

static constexpr int E_ = 8, M_ = 4096, K_ = 2048, N_ = 2048;
static constexpr int KB_ = 16;           // 128-wide k scale blocks
static constexpr int NB128 = N_ / 128;   // weight n-blocks
static constexpr int BM = 256, BN = 256, BK = 128;
static constexpr int KT = K_ / BK;       // 16 K-tiles
static constexpr int MT2 = M_ / BM;      // 16
static constexpr int NT2 = N_ / BN;      // 8
#define FP8MAX 448.0f

// ---------------- quantize x: one scale per (row, 128-k-block) ----------------
__global__ __launch_bounds__(256) void quant_x_kernel(const float* __restrict__ x,
                                                      unsigned char* __restrict__ qx,
                                                      float* __restrict__ sx) {
  long tile = (long)blockIdx.x * 8 + (threadIdx.x >> 5);
  int lane = threadIdx.x & 31;
  f32x4 v = *(const f32x4*)(x + tile * 128 + lane * 4);
  float am = fmaxf(fmaxf(fabsf(v[0]), fabsf(v[1])), fmaxf(fabsf(v[2]), fabsf(v[3])));
#pragma unroll
  for (int off = 16; off; off >>= 1) am = fmaxf(am, __shfl_xor(am, off, 32));
  float safe = fmaxf(am, 1e-4f);
  float qs = FP8MAX / safe;
  int pk = 0;
  pk = __builtin_amdgcn_cvt_pk_fp8_f32(v[0] * qs, v[1] * qs, pk, false);
  pk = __builtin_amdgcn_cvt_pk_fp8_f32(v[2] * qs, v[3] * qs, pk, true);
  *(int*)(qx + tile * 128 + lane * 4) = pk;
  if (lane == 0) sx[tile] = safe / FP8MAX;
}

// ---------------- quantize w: one scale per 128x128 block ----------------
__global__ __launch_bounds__(256) void quant_w_kernel(const float* __restrict__ w,
                                                      unsigned char* __restrict__ qw,
                                                      float* __restrict__ sw) {
  int b = blockIdx.x;
  int kb = b % KB_;
  int t2 = b / KB_;
  int nb = t2 % NB128;
  int e = t2 / NB128;
  int tid = threadIdx.x;
  int r = tid >> 1;
  int c0 = (tid & 1) * 64;
  const float* base = w + ((long)(e * N_ + nb * 128 + r)) * K_ + kb * 128 + c0;
  f32x4 v[16];
  float am = 0.f;
#pragma unroll
  for (int j = 0; j < 16; ++j) {
    v[j] = *(const f32x4*)(base + j * 4);
    am = fmaxf(am, fmaxf(fmaxf(fabsf(v[j][0]), fabsf(v[j][1])),
                         fmaxf(fabsf(v[j][2]), fabsf(v[j][3]))));
  }
#pragma unroll
  for (int off = 32; off; off >>= 1) am = fmaxf(am, __shfl_xor(am, off, 64));
  __shared__ float red[4];
  if ((tid & 63) == 0) red[tid >> 6] = am;
  __syncthreads();
  am = fmaxf(fmaxf(red[0], red[1]), fmaxf(red[2], red[3]));
  float safe = fmaxf(am, 1e-6f);
  float qs = FP8MAX / safe;
  unsigned char* outp = qw + ((long)(e * N_ + nb * 128 + r)) * K_ + kb * 128 + c0;
#pragma unroll
  for (int j4 = 0; j4 < 4; ++j4) {
    uint4 pkv;
    unsigned int* pp = (unsigned int*)&pkv;
#pragma unroll
    for (int q = 0; q < 4; ++q) {
      int j = j4 * 4 + q;
      int pk = 0;
      pk = __builtin_amdgcn_cvt_pk_fp8_f32(v[j][0] * qs, v[j][1] * qs, pk, false);
      pk = __builtin_amdgcn_cvt_pk_fp8_f32(v[j][2] * qs, v[j][3] * qs, pk, true);
      pp[q] = (unsigned int)pk;
    }
    *(uint4*)(outp + j4 * 16) = pkv;
  }
  if (tid == 0) sw[(e * NB128 + nb) * KB_ + kb] = safe / FP8MAX;
}

// ---------------- grouped GEMM: 256x256, 32x32x16 MFMA, ILP-2, 4 mb-phases ----------
__device__ inline void gload16(const void* g, void* l) {
  __builtin_amdgcn_global_load_lds(
      (const __attribute__((address_space(1))) unsigned int*)g,
      (__attribute__((address_space(3))) unsigned int*)l, 16, 0, 0);
}

#define BAR __builtin_amdgcn_s_barrier()

// two independent 8-deep chains (ILP-2): a_mb x {b0, b1}
#define MM2(AV, ACC0, ACC1, SXV)                                                \
  do {                                                                          \
    f32x16 p0 = {0.f, 0.f, 0.f, 0.f, 0.f, 0.f, 0.f, 0.f,                       \
                 0.f, 0.f, 0.f, 0.f, 0.f, 0.f, 0.f, 0.f};                       \
    f32x16 p1 = p0;                                                             \
    __builtin_amdgcn_s_setprio(1);                                              \
    _Pragma("unroll") for (int ks = 0; ks < 8; ++ks) {                          \
      p0 = __builtin_amdgcn_mfma_f32_32x32x16_fp8_fp8(AV[ks], b0[ks], p0, 0, 0, 0); \
      p1 = __builtin_amdgcn_mfma_f32_32x32x16_fp8_fp8(AV[ks], b1[ks], p1, 0, 0, 0); \
    }                                                                           \
    __builtin_amdgcn_s_setprio(0);                                              \
    ACC0 += p0 * (SXV);                                                         \
    ACC1 += p1 * (SXV);                                                         \
  } while (0)

#define RD8(DST, BASE, ROFF)                                                    \
  _Pragma("unroll") for (int ks = 0; ks < 8; ++ks)                              \
      DST[ks] = *(const long*)&(BASE)[(ROFF) + cofs[ks]];

// x-scale vector for mb block: s[r] maps to row (r&3)+8*(r>>2)+4*hi
#define LDSX(SV, MB)                                                            \
  do {                                                                          \
    _Pragma("unroll") for (int g = 0; g < 4; ++g) {                             \
      f32x4 t = *(const f32x4*)&sxl[kt][wr * 128 + (MB) * 32 + hi * 4 + g * 8]; \
      _Pragma("unroll") for (int j = 0; j < 4; ++j) SV[g * 4 + j] = t[j] * swk; \
    }                                                                           \
  } while (0)

__global__ __launch_bounds__(512, 2) void gemm_kernel(
    const unsigned char* __restrict__ qx, const unsigned char* __restrict__ qw,
    const float* __restrict__ sx, const float* __restrict__ sw,
    float* __restrict__ out) {
  __shared__ unsigned char As[2][BM * BK];   // 64 KiB
  __shared__ unsigned char Bs[2][BN * BK];   // 64 KiB
  __shared__ float sxl[KT][BM];              // 16 KiB
  __shared__ float swl[2][KT];

  const int e = blockIdx.y;
  const int x = blockIdx.x;
  const int swz = (x & 7) * 16 + (x >> 3);   // bijective: 128 % 8 == 0
  const int mt = swz >> 3, nt = swz & 7;
  const int brow = mt * BM, bcol = nt * BN;

  const int tid = threadIdx.x;
  const int w = tid >> 6, l = tid & 63;
  const int wr = w >> 2, wc = w & 3;         // 2 (M) x 4 (N); 128x64 C per wave
  const int r32 = l & 31, hi = l >> 5, rx = l & 7;

  const unsigned char* Ab = qx + (size_t)(e * M_ + brow) * K_;
  const unsigned char* Bb = qw + (size_t)(e * N_ + bcol) * K_;

  // ---- stage dequant scales ----
  {
    int row = tid >> 1, h = (tid & 1) * 8;
    const float* sp = sx + (size_t)(e * M_ + brow + row) * KB_ + h;
    f32x4 s0 = *(const f32x4*)sp;
    f32x4 s1 = *(const f32x4*)(sp + 4);
#pragma unroll
    for (int j = 0; j < 4; ++j) {
      sxl[h + j][row] = s0[j];
      sxl[h + 4 + j][row] = s1[j];
    }
    if (tid < 32)
      swl[tid >> 4][tid & 15] =
          sw[(e * NB128 + nt * 2 + (tid >> 4)) * KB_ + (tid & 15)];
  }

  // ---- staging: unit = 64 rows x 128B; 512 thr x 16B; linear LDS dest ----
  const int srcswz = ((l & 7) ^ ((l >> 3) & 7)) * 16;
  auto stageA = [&](int rowbase, int kt2, int tb) {
    gload16(Ab + (size_t)(rowbase + w * 8 + (l >> 3)) * K_ + kt2 * BK + srcswz,
            &As[tb][(rowbase + w * 8) * BK]);
  };
  auto stageB = [&](int rowbase, int kt2, int tb) {
    gload16(Bb + (size_t)(rowbase + w * 8 + (l >> 3)) * K_ + kt2 * BK + srcswz,
            &Bs[tb][(rowbase + w * 8) * BK]);
  };

  // ---- prologue: stage tiles 0,1 (8 loads each); publish tile 0 + scales ----
#pragma unroll
  for (int t = 0; t < 2; ++t) {
    stageA(0, t, t); stageA(64, t, t); stageA(128, t, t); stageA(192, t, t);
    stageB(0, t, t); stageB(64, t, t); stageB(128, t, t); stageB(192, t, t);
  }
  asm volatile("s_waitcnt vmcnt(8) lgkmcnt(0)" ::: "memory");
  BAR;
  __builtin_amdgcn_sched_barrier(0);

  f32x16 acc00 = {0.f}, acc01 = {0.f}, acc10 = {0.f}, acc11 = {0.f};
  f32x16 acc20 = {0.f}, acc21 = {0.f}, acc30 = {0.f}, acc31 = {0.f};
  int cofs[8];
#pragma unroll
  for (int ks = 0; ks < 8; ++ks) cofs[ks] = ((ks ^ rx) * 16) + hi * 8;
  const int arow0 = (wr * 128 + r32) * BK;
  const int brow0 = (wc * 64 + r32) * BK;

  long a0[8], a1[8], a2[8], a3[8], b0[8], b1[8];
  f32x16 sx0, sx1, sx2, sx3;

  for (int kt = 0; kt < KT; ++kt) {
    const int buf = kt & 1;
    const unsigned char* Acur = As[buf];
    const unsigned char* Bcur = Bs[buf];
    const float swk = swl[wc >> 1][kt];

    // P0: mb=0; read B fully + a0
    LDSX(sx0, 0);
    RD8(a0, Acur, arow0);
    RD8(b0, Bcur, brow0);
    RD8(b1, Bcur, brow0 + 32 * BK);
    BAR;
    MM2(a0, acc00, acc01, sx0);
    BAR;
    // P1: mb=1; B consumed by all waves (P0 closing BAR) -> stage kt+2 B
    LDSX(sx1, 1);
    RD8(a1, Acur, arow0 + 32 * BK);
    RD8(a2, Acur, arow0 + 64 * BK);
    if (kt + 2 < KT) { stageB(0, kt + 2, buf); stageB(64, kt + 2, buf);
                       stageB(128, kt + 2, buf); stageB(192, kt + 2, buf); }
    BAR;
    MM2(a1, acc10, acc11, sx1);
    BAR;
    // P2: mb=2 (a2 already in regs); read a3 ahead
    LDSX(sx2, 2);
    RD8(a3, Acur, arow0 + 96 * BK);
    BAR;
    MM2(a2, acc20, acc21, sx2);
    BAR;
    // P3: mb=3; ALL this wave's LDS reads drained, then barrier -> A rows free
    LDSX(sx3, 3);
    asm volatile("s_waitcnt lgkmcnt(0)" ::: "memory");
    BAR;
    __builtin_amdgcn_sched_barrier(0);
    if (kt + 2 < KT) { stageA(0, kt + 2, buf); stageA(64, kt + 2, buf);
                       stageA(128, kt + 2, buf); stageA(192, kt + 2, buf); }
    MM2(a3, acc30, acc31, sx3);
    // drain-then-publish tile kt+1 (8 newest = kt+2's stages stay in flight)
    if (kt < KT - 2) {
      asm volatile("s_waitcnt vmcnt(8)" ::: "memory");
      BAR;
      __builtin_amdgcn_sched_barrier(0);
    } else if (kt == KT - 2) {
      asm volatile("s_waitcnt vmcnt(0)" ::: "memory");
      BAR;
      __builtin_amdgcn_sched_barrier(0);
    }
  }

  // ---- epilogue: 32x32 C/D: col = l&31, row = (r&3)+8*(r>>2)+4*hi (validated) ----
#pragma unroll
  for (int mb = 0; mb < 4; ++mb) {
#pragma unroll
    for (int nb = 0; nb < 2; ++nb) {
      const f32x16 accv =
          mb == 0 ? (nb == 0 ? acc00 : acc01)
        : mb == 1 ? (nb == 0 ? acc10 : acc11)
        : mb == 2 ? (nb == 0 ? acc20 : acc21)
                  : (nb == 0 ? acc30 : acc31);
      const int n = bcol + wc * 64 + nb * 32 + r32;
#pragma unroll
      for (int r = 0; r < 16; ++r) {
        const int m = brow + wr * 128 + mb * 32 + (r & 3) + 8 * (r >> 2) + 4 * hi;
        out[(size_t)(e * M_ + m) * N_ + n] = accv[r];
      }
    }
  }
}

extern "C" void kernel_launch(void* const* d_in, const int* in_sizes, int n_in,
                              void* d_out, int out_size, void* d_ws, size_t ws_size,
                              hipStream_t stream) {
  const float* x = (const float*)d_in[0];
  const float* wt = (const float*)d_in[1];
  float* out = (float*)d_out;

  unsigned char* ws = (unsigned char*)d_ws;
  unsigned char* qx = ws;                               // 64 MiB
  unsigned char* qw = ws + (size_t)E_ * M_ * K_;        // 32 MiB
  float* sx = (float*)(qw + (size_t)E_ * N_ * K_);      // 2 MiB
  float* sw = sx + (size_t)E_ * M_ * KB_;               // 8 KiB

  quant_x_kernel<<<dim3((E_ * M_ * KB_) / 8), dim3(256), 0, stream>>>(x, qx, sx);
  quant_w_kernel<<<dim3(E_ * NB128 * KB_), dim3(256), 0, stream>>>(wt, qw, sw);
  gemm_kernel<<<dim3(MT2 * NT2, E_), dim3(512), 0, stream>>>(qx, qw, sx, sw, out);
}

// Round 6
// 416.200 us; speedup vs baseline: 4.0860x; 4.0860x over previous
//
#include <hip/hip_runtime.h>

typedef float f32x4 __attribute__((ext_vector_type(4)));

static constexpr int E_ = 8, M_ = 4096, K_ = 2048, N_ = 2048;
static constexpr int KB_ = K_ / 128;  // 16 k-blocks
static constexpr int MT_ = M_ / 128;  // 32 m-tiles
static constexpr int NT_ = N_ / 128;  // 16 n-tiles
#define FP8MAX 448.0f

// ---------------- quantize x: one scale per (row, 128-k-block) ----------------
__global__ __launch_bounds__(256) void quant_x_kernel(const float* __restrict__ x,
                                                      unsigned char* __restrict__ qx,
                                                      float* __restrict__ sx) {
  long tile = (long)blockIdx.x * 8 + (threadIdx.x >> 5);
  int lane = threadIdx.x & 31;
  f32x4 v = *(const f32x4*)(x + tile * 128 + lane * 4);
  float am = fmaxf(fmaxf(fabsf(v[0]), fabsf(v[1])), fmaxf(fabsf(v[2]), fabsf(v[3])));
#pragma unroll
  for (int off = 16; off; off >>= 1) am = fmaxf(am, __shfl_xor(am, off, 32));
  float safe = fmaxf(am, 1e-4f);
  float qs = FP8MAX / safe;
  int pk = 0;
  pk = __builtin_amdgcn_cvt_pk_fp8_f32(v[0] * qs, v[1] * qs, pk, false);
  pk = __builtin_amdgcn_cvt_pk_fp8_f32(v[2] * qs, v[3] * qs, pk, true);
  *(int*)(qx + tile * 128 + lane * 4) = pk;
  if (lane == 0) sx[tile] = safe / FP8MAX;
}

// ---------------- quantize w: one scale per 128x128 block ----------------
__global__ __launch_bounds__(256) void quant_w_kernel(const float* __restrict__ w,
                                                      unsigned char* __restrict__ qw,
                                                      float* __restrict__ sw) {
  int b = blockIdx.x;
  int kb = b % KB_;
  int t2 = b / KB_;
  int nb = t2 % NT_;
  int e = t2 / NT_;
  int tid = threadIdx.x;
  int r = tid >> 1;
  int c0 = (tid & 1) * 64;
  const float* base = w + ((long)(e * N_ + nb * 128 + r)) * K_ + kb * 128 + c0;
  f32x4 v[16];
  float am = 0.f;
#pragma unroll
  for (int j = 0; j < 16; ++j) {
    v[j] = *(const f32x4*)(base + j * 4);
    am = fmaxf(am, fmaxf(fmaxf(fabsf(v[j][0]), fabsf(v[j][1])),
                         fmaxf(fabsf(v[j][2]), fabsf(v[j][3]))));
  }
#pragma unroll
  for (int off = 32; off; off >>= 1) am = fmaxf(am, __shfl_xor(am, off, 64));
  __shared__ float red[4];
  if ((tid & 63) == 0) red[tid >> 6] = am;
  __syncthreads();
  am = fmaxf(fmaxf(red[0], red[1]), fmaxf(red[2], red[3]));
  float safe = fmaxf(am, 1e-6f);
  float qs = FP8MAX / safe;
  unsigned char* outp = qw + ((long)(e * N_ + nb * 128 + r)) * K_ + kb * 128 + c0;
#pragma unroll
  for (int j4 = 0; j4 < 4; ++j4) {
    uint4 pkv;
    unsigned int* pp = (unsigned int*)&pkv;
#pragma unroll
    for (int q = 0; q < 4; ++q) {
      int j = j4 * 4 + q;
      int pk = 0;
      pk = __builtin_amdgcn_cvt_pk_fp8_f32(v[j][0] * qs, v[j][1] * qs, pk, false);
      pk = __builtin_amdgcn_cvt_pk_fp8_f32(v[j][2] * qs, v[j][3] * qs, pk, true);
      pp[q] = (unsigned int)pk;
    }
    *(uint4*)(outp + j4 * 16) = pkv;
  }
  if (tid == 0) sw[(e * NT_ + nb) * KB_ + kb] = safe / FP8MAX;
}

// -------- grouped GEMM: round-1 structure + LDS double-buffer prefetch --------
__device__ inline void gload16(const void* g, void* l) {
  __builtin_amdgcn_global_load_lds(
      (const __attribute__((address_space(1))) unsigned int*)g,
      (__attribute__((address_space(3))) unsigned int*)l, 16, 0, 0);
}

__global__ __launch_bounds__(256, 2) void gemm_kernel(
    const unsigned char* __restrict__ qx, const unsigned char* __restrict__ qw,
    const float* __restrict__ sx, const float* __restrict__ sw,
    float* __restrict__ out) {
  __shared__ unsigned char As[2][128 * 128];  // 32 KiB (double-buffered)
  __shared__ unsigned char Bs[2][128 * 128];  // 32 KiB
  __shared__ float sxl[128][17];              // x scales [row][kb], padded
  __shared__ float swl[16];                   // w scales for this n-block

  const int e = blockIdx.y;
  const int mt = blockIdx.x / NT_;
  const int nt = blockIdx.x % NT_;
  const int brow = mt * 128, bcol = nt * 128;
  const int tid = threadIdx.x;
  const int w = tid >> 6, l = tid & 63;
  const int wr = w >> 1, wc = w & 1;        // wave quadrant (2x2 of 64x64)
  const int qq = l >> 4, rl = l & 15;       // quarter-wave, lane-in-16

  // stage scales into LDS
  {
    int row = tid >> 1, half = (tid & 1) * 8;
    const float* sp = sx + ((long)(e * M_ + brow + row)) * KB_ + half;
    f32x4 s0 = *(const f32x4*)sp;
    f32x4 s1 = *(const f32x4*)(sp + 4);
#pragma unroll
    for (int j = 0; j < 4; ++j) {
      sxl[row][half + j] = s0[j];
      sxl[row][half + 4 + j] = s1[j];
    }
    if (tid < KB_) swl[tid] = sw[(e * NT_ + nt) * KB_ + tid];
  }

  f32x4 acc[4][4] = {};

  const unsigned char* Ab = qx + (long)(e * M_ + brow) * K_;
  const unsigned char* Bb = qw + (long)(e * N_ + bcol) * K_;
  const int lr8 = l >> 3, lc8 = l & 7;
  const int sch = (lc8 ^ lr8) * 16;   // pre-swizzled source chunk (linear LDS dest)
  const int o8 = (qq & 1) * 8;
  const int ch = qq >> 1;

  // ---- prologue: stage tile 0 into buffer 0, publish with full barrier ----
#pragma unroll
  for (int i = 0; i < 4; ++i) {
    const int rt = i * 32 + w * 8;
    gload16(Ab + (long)(rt + lr8) * K_ + sch, &As[0][rt * 128]);
    gload16(Bb + (long)(rt + lr8) * K_ + sch, &Bs[0][rt * 128]);
  }
  __syncthreads();   // drains vmcnt(0)+lgkmcnt(0): tile 0 + scales visible

  for (int kb = 0; kb < KB_; ++kb) {
    const unsigned char* Acur = As[kb & 1];
    const unsigned char* Bcur = Bs[kb & 1];

    // issue prefetch of tile kb+1 into the other buffer FIRST; it lands
    // during this iteration's fragment reads + MFMA.
    if (kb + 1 < KB_) {
#pragma unroll
      for (int i = 0; i < 4; ++i) {
        const int rt = i * 32 + w * 8;
        gload16(Ab + (long)(rt + lr8) * K_ + (kb + 1) * 128 + sch,
                &As[(kb + 1) & 1][rt * 128]);
        gload16(Bb + (long)(rt + lr8) * K_ + (kb + 1) * 128 + sch,
                &Bs[(kb + 1) & 1][rt * 128]);
      }
    }

    // fragment loads: ds_read_b64, swizzle-corrected
    long af[4][4], bf[4][4];
#pragma unroll
    for (int f = 0; f < 4; ++f) {
      const int ra = wr * 64 + f * 16 + rl;
      const int rb = wc * 64 + f * 16 + rl;
      const int rxa = ra & 7, rxb = rb & 7;
#pragma unroll
      for (int ks = 0; ks < 4; ++ks) {
        const int c = ks * 2 + ch;
        af[f][ks] = *(const long*)(Acur + ra * 128 + ((c ^ rxa) * 16) + o8);
        bf[f][ks] = *(const long*)(Bcur + rb * 128 + ((c ^ rxb) * 16) + o8);
      }
    }

    const float swk = swl[kb];
    float sxs[4][4];
#pragma unroll
    for (int mf = 0; mf < 4; ++mf)
#pragma unroll
      for (int r = 0; r < 4; ++r)
        sxs[mf][r] = sxl[wr * 64 + mf * 16 + qq * 4 + r][kb] * swk;

    __builtin_amdgcn_s_setprio(1);
#pragma unroll
    for (int mf = 0; mf < 4; ++mf)
#pragma unroll
      for (int nf = 0; nf < 4; ++nf) {
        f32x4 p = {0.f, 0.f, 0.f, 0.f};
#pragma unroll
        for (int ks = 0; ks < 4; ++ks)
          p = __builtin_amdgcn_mfma_f32_16x16x32_fp8_fp8(af[mf][ks], bf[nf][ks], p, 0, 0, 0);
#pragma unroll
        for (int r = 0; r < 4; ++r) acc[mf][nf][r] += p[r] * sxs[mf][r];
      }
    __builtin_amdgcn_s_setprio(0);

    // single per-K-step boundary: drains my prefetch (vmcnt) and my LDS reads
    // (lgkmcnt), then barrier -> tile kb+1 published, buffer kb reusable.
    __syncthreads();
  }

  // epilogue: C row = (l>>4)*4 + r, col = l&15 (validated rounds 1-5)
#pragma unroll
  for (int mf = 0; mf < 4; ++mf) {
    const int m = brow + wr * 64 + mf * 16 + qq * 4;
#pragma unroll
    for (int nf = 0; nf < 4; ++nf) {
      const int n = bcol + wc * 64 + nf * 16 + rl;
      float* op = out + ((long)(e * M_ + m)) * N_ + n;
#pragma unroll
      for (int r = 0; r < 4; ++r) op[(long)r * N_] = acc[mf][nf][r];
    }
  }
}

extern "C" void kernel_launch(void* const* d_in, const int* in_sizes, int n_in,
                              void* d_out, int out_size, void* d_ws, size_t ws_size,
                              hipStream_t stream) {
  const float* x = (const float*)d_in[0];
  const float* wt = (const float*)d_in[1];
  float* out = (float*)d_out;

  unsigned char* ws = (unsigned char*)d_ws;
  unsigned char* qx = ws;                               // 64 MiB
  unsigned char* qw = ws + (size_t)E_ * M_ * K_;        // 32 MiB
  float* sx = (float*)(qw + (size_t)E_ * N_ * K_);      // 2 MiB
  float* sw = sx + (size_t)E_ * M_ * KB_;               // 8 KiB

  quant_x_kernel<<<dim3((E_ * M_ * KB_) / 8), dim3(256), 0, stream>>>(x, qx, sx);
  quant_w_kernel<<<dim3(E_ * NT_ * KB_), dim3(256), 0, stream>>>(wt, qw, sw);
  gemm_kernel<<<dim3(MT_ * NT_, E_), dim3(256), 0, stream>>>(qx, qw, sx, sw, out);
}